// Round 4
// baseline (314.292 us; speedup 1.0000x reference)
//
#include <hip/hip_runtime.h>
#include <math.h>

#define HIST_CHUNK 8192

typedef __attribute__((ext_vector_type(8))) short bf16x8;
typedef __attribute__((ext_vector_type(4))) float f32x4;
typedef __attribute__((ext_vector_type(2))) float f32x2;

__device__ __forceinline__ unsigned short f2bf(float f){
  unsigned int u = __float_as_uint(f);
  unsigned int r = (u + 0x7FFFu + ((u >> 16) & 1u)) >> 16;   // RNE
  return (unsigned short)r;
}

// pack 8 f32 -> bf16x8 via v_cvt_pk_bf16_f32 (RNE, 1 inst / 2 floats)
__device__ __forceinline__ bf16x8 cvt8(float4 a, float4 b){
  union { unsigned u[4]; bf16x8 v; } r;
  asm("v_cvt_pk_bf16_f32 %0, %1, %2" : "=v"(r.u[0]) : "v"(a.x), "v"(a.y));
  asm("v_cvt_pk_bf16_f32 %0, %1, %2" : "=v"(r.u[1]) : "v"(a.z), "v"(a.w));
  asm("v_cvt_pk_bf16_f32 %0, %1, %2" : "=v"(r.u[2]) : "v"(b.x), "v"(b.y));
  asm("v_cvt_pk_bf16_f32 %0, %1, %2" : "=v"(r.u[3]) : "v"(b.z), "v"(b.w));
  return r.v;
}

// ---------------- one-time prep: W1^T bf16, W2^T bf16 (padded 48), zero deg ----------------
__global__ void k_prep(const float* __restrict__ W1, const float* __restrict__ W2,
                       unsigned short* __restrict__ w1t, unsigned short* __restrict__ w2t,
                       int* __restrict__ deg, int NPAD){
  int t = threadIdx.x, b = blockIdx.x;
  if(b == 0){
    for(int i = t; i < 8192; i += 256){
      int k = i >> 6, f = i & 63;
      w1t[f*128 + k] = f2bf(W1[i]);
    }
  } else if(b == 1){
    for(int i = t; i < 3072; i += 256){
      int c = i >> 6, k = i & 63;
      w2t[c*64 + k] = (c < 40) ? f2bf(W2[k*40 + c]) : (unsigned short)0;
    }
  } else {
    int i = (b-2)*256 + t;
    if(i < NPAD) deg[i] = 0;
  }
}

// ---------------- CSR build: direct global-atomic hist + 3-phase scan + scatter ----------------

__global__ __launch_bounds__(256) void k_hist(const int* __restrict__ dst, int E,
                                              int* __restrict__ deg){
  int base = blockIdx.x*HIST_CHUNK;
  int end = base + HIST_CHUNK; if(end > E) end = E;
  for(int i = base + threadIdx.x; i < end; i += 256)
    atomicAdd(&deg[dst[i]], 1);
}

// per-256-node block sums
__global__ __launch_bounds__(256) void k_s1(const int* __restrict__ deg,
                                            int* __restrict__ bsum){
  __shared__ int ws[4];
  int b = blockIdx.x, t = threadIdx.x;
  int v = deg[b*256 + t];
  v += __shfl_down(v, 32, 64); v += __shfl_down(v, 16, 64);
  v += __shfl_down(v,  8, 64); v += __shfl_down(v,  4, 64);
  v += __shfl_down(v,  2, 64); v += __shfl_down(v,  1, 64);
  if((t & 63) == 0) ws[t >> 6] = v;
  __syncthreads();
  if(t == 0) bsum[b] = ws[0] + ws[1] + ws[2] + ws[3];
}

// scan of block sums -> bofs (exclusive), bofs[NBK]=E
__global__ void k_s2(const int* __restrict__ bsum, int* __restrict__ bofs,
                     int NBK, int E){
  __shared__ int sh[1024];
  int t = threadIdx.x;
  int c0 = (2*t   < NBK) ? bsum[2*t]   : 0;
  int c1 = (2*t+1 < NBK) ? bsum[2*t+1] : 0;
  sh[t] = c0 + c1; __syncthreads();
  for(int off = 1; off < 1024; off <<= 1){
    int v = (t >= off) ? sh[t - off] : 0;
    __syncthreads();
    sh[t] += v;
    __syncthreads();
  }
  int pairEx = sh[t] - (c0 + c1);
  if(2*t   < NBK) bofs[2*t]   = pairEx;
  if(2*t+1 < NBK) bofs[2*t+1] = pairEx + c0;
  if(t == 0) bofs[NBK] = E;
}

// per-node offsets: row_ofs, cur, dinv
__global__ __launch_bounds__(256) void k_s3(const int* __restrict__ deg,
     const int* __restrict__ bofs, int* __restrict__ row_ofs, int* __restrict__ cur,
     float* __restrict__ dinv, int N, int E, int NBK){
  __shared__ int wsum[4];
  int b = blockIdx.x, t = threadIdx.x;
  int c = deg[b*256 + t];
  int lane = t & 63, wid = t >> 6;
  int v = c;
  #pragma unroll
  for(int off = 1; off < 64; off <<= 1){
    int nv = __shfl_up(v, off, 64);
    if(lane >= off) v += nv;
  }
  if(lane == 63) wsum[wid] = v;
  __syncthreads();
  int wpre = 0;
  #pragma unroll
  for(int k2 = 0; k2 < 4; k2++) if(k2 < wid) wpre += wsum[k2];
  int ex = wpre + v - c;
  int node = b*256 + t;
  if(node < N){
    int ro = bofs[b] + ex;
    row_ofs[node] = ro;
    cur[node] = ro;
    dinv[node] = rsqrtf((float)(c + 1));   // +1 self loop
  }
  if(b == NBK-1 && t == 0) row_ofs[N] = E;
}

__global__ __launch_bounds__(256) void k_scatter(const int* __restrict__ src,
     const int* __restrict__ dst, int E, int* __restrict__ cur, int* __restrict__ csr){
  int base = blockIdx.x*HIST_CHUNK;
  int end = base + HIST_CHUNK; if(end > E) end = E;
  for(int i = base + threadIdx.x; i < end; i += 256){
    int d = dst[i];
    int pos = atomicAdd(&cur[d], 1);
    csr[pos] = src[i];
  }
}

// ---------------- GEMM1 (MFMA bf16): g1 = fp8( dinv * (x @ W1) ) ----------------
// 128 nodes/block. Both operands staged coalesced into LDS:
//   W1^T bf16 from prepped w1t (uint4), x via float4 + v_cvt_pk_bf16_f32.
__global__ __launch_bounds__(256) void k_gemm1(const float* __restrict__ x,
                        const unsigned short* __restrict__ w1t,
                        const float* __restrict__ dinv, unsigned int* __restrict__ g1, int n){
  __shared__ unsigned short xs[128*136];  // x tile bf16 [node][k]
  __shared__ unsigned short wt[64*136];   // W1^T bf16 [feat][k]
  int tid = threadIdx.x;
  int nodeBase = blockIdx.x*128;
  for(int i = tid; i < 1024; i += 256){
    int f = i >> 4, seg = i & 15;
    *(uint4*)&wt[f*136 + seg*8] = *(const uint4*)&w1t[f*128 + seg*8];
  }
  {
    const float4* x4 = (const float4*)x;
    for(int i = tid; i < 2048; i += 256){
      int node = i >> 4, seg = i & 15;     // 8 floats per chunk
      float4 va = make_float4(0.f,0.f,0.f,0.f), vb = va;
      if(nodeBase + node < n){
        va = x4[(size_t)(nodeBase + node)*32 + seg*2];
        vb = x4[(size_t)(nodeBase + node)*32 + seg*2 + 1];
      }
      *(bf16x8*)&xs[node*136 + seg*8] = cvt8(va, vb);
    }
  }
  __syncthreads();

  int w = tid >> 6, lane = tid & 63;
  int ml = lane & 15, q = lane >> 4;
  int n0 = nodeBase + w*32 + ml;
  int n1 = n0 + 16;
  bool vn0 = n0 < n, vn1 = n1 < n;

  f32x4 a00 = {0.f,0.f,0.f,0.f}, a01 = {0.f,0.f,0.f,0.f},
        a02 = {0.f,0.f,0.f,0.f}, a03 = {0.f,0.f,0.f,0.f};
  f32x4 a10 = {0.f,0.f,0.f,0.f}, a11 = {0.f,0.f,0.f,0.f},
        a12 = {0.f,0.f,0.f,0.f}, a13 = {0.f,0.f,0.f,0.f};
  const unsigned short* brow = &xs[(w*32 + ml)*136 + q*8];
  const unsigned short* arow = &wt[ml*136 + q*8];
  #pragma unroll
  for(int s = 0; s < 4; s++){
    bf16x8 bb0 = *(const bf16x8*)(brow +        s*32);
    bf16x8 bb1 = *(const bf16x8*)(brow + 2176 + s*32);   // +16*136
    bf16x8 a0 = *(const bf16x8*)(arow +    0 + s*32);
    bf16x8 a1 = *(const bf16x8*)(arow + 2176 + s*32);
    bf16x8 a2 = *(const bf16x8*)(arow + 4352 + s*32);
    bf16x8 a3 = *(const bf16x8*)(arow + 6528 + s*32);
    a00 = __builtin_amdgcn_mfma_f32_16x16x32_bf16(a0, bb0, a00, 0, 0, 0);
    a01 = __builtin_amdgcn_mfma_f32_16x16x32_bf16(a1, bb0, a01, 0, 0, 0);
    a02 = __builtin_amdgcn_mfma_f32_16x16x32_bf16(a2, bb0, a02, 0, 0, 0);
    a03 = __builtin_amdgcn_mfma_f32_16x16x32_bf16(a3, bb0, a03, 0, 0, 0);
    a10 = __builtin_amdgcn_mfma_f32_16x16x32_bf16(a0, bb1, a10, 0, 0, 0);
    a11 = __builtin_amdgcn_mfma_f32_16x16x32_bf16(a1, bb1, a11, 0, 0, 0);
    a12 = __builtin_amdgcn_mfma_f32_16x16x32_bf16(a2, bb1, a12, 0, 0, 0);
    a13 = __builtin_amdgcn_mfma_f32_16x16x32_bf16(a3, bb1, a13, 0, 0, 0);
  }
  if(vn0){
    float dv = dinv[n0];
    unsigned base16 = ((unsigned)n0 << 4) + q;
    int p;
    p = __builtin_amdgcn_cvt_pk_fp8_f32(a00[0]*dv, a00[1]*dv, 0, false);
    p = __builtin_amdgcn_cvt_pk_fp8_f32(a00[2]*dv, a00[3]*dv, p, true);
    g1[base16 +  0] = (unsigned)p;
    p = __builtin_amdgcn_cvt_pk_fp8_f32(a01[0]*dv, a01[1]*dv, 0, false);
    p = __builtin_amdgcn_cvt_pk_fp8_f32(a01[2]*dv, a01[3]*dv, p, true);
    g1[base16 +  4] = (unsigned)p;
    p = __builtin_amdgcn_cvt_pk_fp8_f32(a02[0]*dv, a02[1]*dv, 0, false);
    p = __builtin_amdgcn_cvt_pk_fp8_f32(a02[2]*dv, a02[3]*dv, p, true);
    g1[base16 +  8] = (unsigned)p;
    p = __builtin_amdgcn_cvt_pk_fp8_f32(a03[0]*dv, a03[1]*dv, 0, false);
    p = __builtin_amdgcn_cvt_pk_fp8_f32(a03[2]*dv, a03[3]*dv, p, true);
    g1[base16 + 12] = (unsigned)p;
  }
  if(vn1){
    float dv = dinv[n1];
    unsigned base16 = ((unsigned)n1 << 4) + q;
    int p;
    p = __builtin_amdgcn_cvt_pk_fp8_f32(a10[0]*dv, a10[1]*dv, 0, false);
    p = __builtin_amdgcn_cvt_pk_fp8_f32(a10[2]*dv, a10[3]*dv, p, true);
    g1[base16 +  0] = (unsigned)p;
    p = __builtin_amdgcn_cvt_pk_fp8_f32(a11[0]*dv, a11[1]*dv, 0, false);
    p = __builtin_amdgcn_cvt_pk_fp8_f32(a11[2]*dv, a11[3]*dv, p, true);
    g1[base16 +  4] = (unsigned)p;
    p = __builtin_amdgcn_cvt_pk_fp8_f32(a12[0]*dv, a12[1]*dv, 0, false);
    p = __builtin_amdgcn_cvt_pk_fp8_f32(a12[2]*dv, a12[3]*dv, p, true);
    g1[base16 +  8] = (unsigned)p;
    p = __builtin_amdgcn_cvt_pk_fp8_f32(a13[0]*dv, a13[1]*dv, 0, false);
    p = __builtin_amdgcn_cvt_pk_fp8_f32(a13[2]*dv, a13[3]*dv, p, true);
    g1[base16 + 12] = (unsigned)p;
  }
}

// ---------------- fused agg1 + gemm2: gather into LDS, then MFMA -> g2 ----------------
// 64 nodes/block. Phase 1: each 16-lane quarter gathers 4 nodes serially
// (lane f owns feats 4f..4f+3), u-row = bf16(dinv*relu(dinv*sum+b1)) -> LDS.
// Phase 2: 6 MFMAs/wave (classes padded to 48) -> fp8 g2 (40-B rows).
__global__ __launch_bounds__(256) void k_agg1g2(const unsigned* __restrict__ g1,
    const int* __restrict__ row_ofs, const int* __restrict__ csr,
    const float* __restrict__ dinv, const float* __restrict__ b1,
    const unsigned short* __restrict__ w2t, unsigned char* __restrict__ g2, int n){
  __shared__ unsigned short us[64*72];    // u tile bf16 [node][k]
  __shared__ unsigned short ws2[48*72];   // W2^T bf16 [class][k]
  int t = threadIdx.x;
  int nodeBase = blockIdx.x*64;
  for(int i = t; i < 384; i += 256){
    int row = i >> 3, seg = i & 7;
    *(uint4*)&ws2[row*72 + seg*8] = *(const uint4*)&w2t[row*64 + seg*8];
  }
  int lane = t & 63;
  int f = lane & 15;
  int bq = (lane & 48) << 2;              // bpermute byte-addr base of own quarter
  int qg = t >> 4;                        // quarter index in block, 0..15
  float4 bb1 = ((const float4*)b1)[f];
  #pragma unroll 1
  for(int i = 0; i < 4; i++){
    int node = nodeBase + qg*4 + i;
    int lrow = qg*4 + i;
    if(node < n){
      int beg = row_ofs[node], end = row_ofs[node+1];
      unsigned v = g1[((unsigned)node << 4) + f];        // self row (once)
      f32x2 s01 = __builtin_amdgcn_cvt_pk_f32_fp8(v, false);
      f32x2 s23 = __builtin_amdgcn_cvt_pk_f32_fp8(v, true);
      for(int e = beg; e < end; e += 16){
        int rem = end - e; if(rem > 16) rem = 16;
        int idxv = (f < rem) ? csr[e + f] : 0;
        int j = 0;
        for(; j + 4 <= rem; j += 4){
          int r0 = __builtin_amdgcn_ds_bpermute(bq + ((j+0) << 2), idxv);
          int r1 = __builtin_amdgcn_ds_bpermute(bq + ((j+1) << 2), idxv);
          int r2 = __builtin_amdgcn_ds_bpermute(bq + ((j+2) << 2), idxv);
          int r3 = __builtin_amdgcn_ds_bpermute(bq + ((j+3) << 2), idxv);
          unsigned v0 = g1[((unsigned)r0 << 4) + f];
          unsigned v1 = g1[((unsigned)r1 << 4) + f];
          unsigned v2 = g1[((unsigned)r2 << 4) + f];
          unsigned v3 = g1[((unsigned)r3 << 4) + f];
          s01 += __builtin_amdgcn_cvt_pk_f32_fp8(v0, false);
          s23 += __builtin_amdgcn_cvt_pk_f32_fp8(v0, true);
          s01 += __builtin_amdgcn_cvt_pk_f32_fp8(v1, false);
          s23 += __builtin_amdgcn_cvt_pk_f32_fp8(v1, true);
          s01 += __builtin_amdgcn_cvt_pk_f32_fp8(v2, false);
          s23 += __builtin_amdgcn_cvt_pk_f32_fp8(v2, true);
          s01 += __builtin_amdgcn_cvt_pk_f32_fp8(v3, false);
          s23 += __builtin_amdgcn_cvt_pk_f32_fp8(v3, true);
        }
        for(; j < rem; j++){
          int r0 = __builtin_amdgcn_ds_bpermute(bq + (j << 2), idxv);
          unsigned v0 = g1[((unsigned)r0 << 4) + f];
          s01 += __builtin_amdgcn_cvt_pk_f32_fp8(v0, false);
          s23 += __builtin_amdgcn_cvt_pk_f32_fp8(v0, true);
        }
      }
      float dv = dinv[node];
      float h0 = fmaxf(fmaf(dv, s01.x, bb1.x), 0.f);
      float h1 = fmaxf(fmaf(dv, s01.y, bb1.y), 0.f);
      float h2 = fmaxf(fmaf(dv, s23.x, bb1.z), 0.f);
      float h3 = fmaxf(fmaf(dv, s23.y, bb1.w), 0.f);
      unsigned p0, p1;
      asm("v_cvt_pk_bf16_f32 %0, %1, %2" : "=v"(p0) : "v"(dv*h0), "v"(dv*h1));
      asm("v_cvt_pk_bf16_f32 %0, %1, %2" : "=v"(p1) : "v"(dv*h2), "v"(dv*h3));
      *(uint2*)&us[lrow*72 + f*4] = make_uint2(p0, p1);
    } else {
      *(uint2*)&us[lrow*72 + f*4] = make_uint2(0u, 0u);
    }
  }
  __syncthreads();
  // ---- MFMA phase (classes padded to 48) ----
  int w = t >> 6;
  int ml = lane & 15, q = lane >> 4;
  f32x4 acc0 = {0.f,0.f,0.f,0.f}, acc1 = {0.f,0.f,0.f,0.f}, acc2 = {0.f,0.f,0.f,0.f};
  const unsigned short* brow = &us[(w*16 + ml)*72 + q*8];
  const unsigned short* a0r = &ws2[ml*72 + q*8];
  #pragma unroll
  for(int s = 0; s < 2; s++){
    bf16x8 bb = *(const bf16x8*)(brow + s*32);
    bf16x8 a0 = *(const bf16x8*)(a0r +    0 + s*32);
    bf16x8 a1 = *(const bf16x8*)(a0r + 1152 + s*32);   // +16*72
    bf16x8 a2 = *(const bf16x8*)(a0r + 2304 + s*32);   // +32*72
    acc0 = __builtin_amdgcn_mfma_f32_16x16x32_bf16(a0, bb, acc0, 0, 0, 0);
    acc1 = __builtin_amdgcn_mfma_f32_16x16x32_bf16(a1, bb, acc1, 0, 0, 0);
    acc2 = __builtin_amdgcn_mfma_f32_16x16x32_bf16(a2, bb, acc2, 0, 0, 0);
  }
  // D: col = node (ml), row = class = ctile*16 + q*4 + r -> row dword = ctile*4 + q
  int node = nodeBase + w*16 + ml;
  if(node < n){
    unsigned* gd = (unsigned*)g2;
    unsigned rb = (unsigned)node*10u + q;
    int p;
    p = __builtin_amdgcn_cvt_pk_fp8_f32(acc0[0], acc0[1], 0, false);
    p = __builtin_amdgcn_cvt_pk_fp8_f32(acc0[2], acc0[3], p, true);
    gd[rb + 0] = (unsigned)p;
    p = __builtin_amdgcn_cvt_pk_fp8_f32(acc1[0], acc1[1], 0, false);
    p = __builtin_amdgcn_cvt_pk_fp8_f32(acc1[2], acc1[3], p, true);
    gd[rb + 4] = (unsigned)p;
    if(q < 2){
      p = __builtin_amdgcn_cvt_pk_fp8_f32(acc2[0], acc2[1], 0, false);
      p = __builtin_amdgcn_cvt_pk_fp8_f32(acc2[2], acc2[3], p, true);
      gd[rb + 8] = (unsigned)p;
    }
  }
}

// ---------------- agg2: node-per-quarter gather + bias + log_softmax ----------------
__global__ __launch_bounds__(256) void k_agg2(const unsigned char* __restrict__ g2,
     const int* __restrict__ row_ofs, const int* __restrict__ csr,
     const float* __restrict__ dinv, const float* __restrict__ b2,
     float* __restrict__ out, int N){
  int t = threadIdx.x;
  int lane = t & 63;
  int f = lane & 15;
  int fc = (f < 10) ? f : 0;              // f>=10 lanes duplicate dword0, discarded
  int bq = (lane & 48) << 2;
  int node = blockIdx.x*16 + (t >> 4);
  if(node >= N) return;
  int beg = row_ofs[node], end = row_ofs[node+1];
  const unsigned* gd = (const unsigned*)g2;   // row = 10 dwords (40 fp8)
  unsigned v = gd[(unsigned)node*10u + fc];   // self row
  f32x2 s01 = __builtin_amdgcn_cvt_pk_f32_fp8(v, false);
  f32x2 s23 = __builtin_amdgcn_cvt_pk_f32_fp8(v, true);
  for(int e = beg; e < end; e += 16){
    int rem = end - e; if(rem > 16) rem = 16;
    int idxv = (f < rem) ? csr[e + f] : 0;
    int j = 0;
    for(; j + 4 <= rem; j += 4){
      int r0 = __builtin_amdgcn_ds_bpermute(bq + ((j+0) << 2), idxv);
      int r1 = __builtin_amdgcn_ds_bpermute(bq + ((j+1) << 2), idxv);
      int r2 = __builtin_amdgcn_ds_bpermute(bq + ((j+2) << 2), idxv);
      int r3 = __builtin_amdgcn_ds_bpermute(bq + ((j+3) << 2), idxv);
      unsigned v0 = gd[(unsigned)r0*10u + fc];
      unsigned v1 = gd[(unsigned)r1*10u + fc];
      unsigned v2 = gd[(unsigned)r2*10u + fc];
      unsigned v3 = gd[(unsigned)r3*10u + fc];
      s01 += __builtin_amdgcn_cvt_pk_f32_fp8(v0, false);
      s23 += __builtin_amdgcn_cvt_pk_f32_fp8(v0, true);
      s01 += __builtin_amdgcn_cvt_pk_f32_fp8(v1, false);
      s23 += __builtin_amdgcn_cvt_pk_f32_fp8(v1, true);
      s01 += __builtin_amdgcn_cvt_pk_f32_fp8(v2, false);
      s23 += __builtin_amdgcn_cvt_pk_f32_fp8(v2, true);
      s01 += __builtin_amdgcn_cvt_pk_f32_fp8(v3, false);
      s23 += __builtin_amdgcn_cvt_pk_f32_fp8(v3, true);
    }
    for(; j < rem; j++){
      int r0 = __builtin_amdgcn_ds_bpermute(bq + (j << 2), idxv);
      unsigned v0 = gd[(unsigned)r0*10u + fc];
      s01 += __builtin_amdgcn_cvt_pk_f32_fp8(v0, false);
      s23 += __builtin_amdgcn_cvt_pk_f32_fp8(v0, true);
    }
  }
  float dv = dinv[node];
  float4 bb = ((const float4*)b2)[fc];
  float l0 = fmaf(dv, s01.x, bb.x);
  float l1 = fmaf(dv, s01.y, bb.y);
  float l2 = fmaf(dv, s23.x, bb.z);
  float l3 = fmaf(dv, s23.y, bb.w);
  bool valid = (f < 10);
  float m = valid ? fmaxf(fmaxf(l0,l1), fmaxf(l2,l3)) : -INFINITY;
  m = fmaxf(m, __shfl_xor(m,1,64)); m = fmaxf(m, __shfl_xor(m,2,64));
  m = fmaxf(m, __shfl_xor(m,4,64)); m = fmaxf(m, __shfl_xor(m,8,64));
  float ex = valid ? (expf(l0-m)+expf(l1-m)) + (expf(l2-m)+expf(l3-m)) : 0.f;
  ex += __shfl_xor(ex,1,64); ex += __shfl_xor(ex,2,64);
  ex += __shfl_xor(ex,4,64); ex += __shfl_xor(ex,8,64);
  float ll = logf(ex);
  if(valid){
    ((float4*)out)[(unsigned)node*10u + f] = make_float4(l0-m-ll, l1-m-ll, l2-m-ll, l3-m-ll);
  }
}

// ---------------- launch ----------------

extern "C" void kernel_launch(void* const* d_in, const int* in_sizes, int n_in,
                              void* d_out, int out_size, void* d_ws, size_t ws_size,
                              hipStream_t stream){
  const float* x  = (const float*)d_in[0];
  const int*   ei = (const int*)  d_in[1];
  const float* W1 = (const float*)d_in[2];
  const float* b1 = (const float*)d_in[3];
  const float* W2 = (const float*)d_in[4];
  const float* b2 = (const float*)d_in[5];
  float* out = (float*)d_out;

  int N = in_sizes[0] / 128;        // 100000
  int E = in_sizes[1] / 2;          // 1600000
  const int* src = ei;
  const int* dst = ei + E;
  int NBK = (N + 255) >> 8;         // 391 scan blocks
  int NPAD = NBK << 8;              // padded node count

  char* w = (char*)d_ws;
  auto alloc = [&](size_t bytes) -> char* {
    char* p = w;
    w += (bytes + 511) & ~(size_t)511;
    return p;
  };
  int*   deg     = (int*)  alloc((size_t)NPAD*4);
  int*   bsum    = (int*)  alloc((size_t)NBK*4);
  int*   bofs    = (int*)  alloc((size_t)(NBK+1)*4);
  int*   row_ofs = (int*)  alloc((size_t)(N+1)*4);
  int*   cur     = (int*)  alloc((size_t)N*4);
  float* dinv    = (float*)alloc((size_t)N*4);
  int*   csr     = (int*)  alloc((size_t)E*4);
  unsigned int*   g1 = (unsigned int*)  alloc((size_t)N*64);   // fp8, 64 B rows
  unsigned char*  g2 = (unsigned char*) alloc((size_t)N*40);   // fp8, 40 B rows
  unsigned short* w1t = (unsigned short*)alloc((size_t)64*128*2); // W1^T bf16
  unsigned short* w2t = (unsigned short*)alloc((size_t)48*64*2);  // W2^T bf16 (padded)

  k_prep    <<<NBK+2, 256, 0, stream>>>(W1, W2, w1t, w2t, deg, NPAD);
  k_hist    <<<(E+HIST_CHUNK-1)/HIST_CHUNK, 256, 0, stream>>>(dst, E, deg);
  k_s1      <<<NBK, 256, 0, stream>>>(deg, bsum);
  k_s2      <<<1, 1024, 0, stream>>>(bsum, bofs, NBK, E);
  k_s3      <<<NBK, 256, 0, stream>>>(deg, bofs, row_ofs, cur, dinv, N, E, NBK);
  k_scatter <<<(E+HIST_CHUNK-1)/HIST_CHUNK, 256, 0, stream>>>(src, dst, E, cur, csr);

  k_gemm1   <<<(N+127)/128, 256, 0, stream>>>(x, w1t, dinv, g1, N);
  k_agg1g2  <<<(N+63)/64, 256, 0, stream>>>(g1, row_ofs, csr, dinv, b1, w2t, g2, N);
  k_agg2    <<<(N+15)/16, 256, 0, stream>>>(g2, row_ofs, csr, dinv, b2, out, N);
}

// Round 5
// 228.128 us; speedup vs baseline: 1.3777x; 1.3777x over previous
//
#include <hip/hip_runtime.h>
#include <math.h>

#define NPB 256           // nodes per bucket
#define BSH 8
#define MAXNB 400
#define BIN_CHUNK 8192
#define HIST_CHUNK 16384

typedef __attribute__((ext_vector_type(8))) short bf16x8;
typedef __attribute__((ext_vector_type(4))) float f32x4;
typedef __attribute__((ext_vector_type(2))) float f32x2;

__device__ __forceinline__ unsigned short f2bf(float f){
  unsigned int u = __float_as_uint(f);
  unsigned int r = (u + 0x7FFFu + ((u >> 16) & 1u)) >> 16;   // RNE
  return (unsigned short)r;
}

// pack 8 f32 -> bf16x8 via v_cvt_pk_bf16_f32 (RNE, 1 inst / 2 floats)
__device__ __forceinline__ bf16x8 cvt8(float4 a, float4 b){
  union { unsigned u[4]; bf16x8 v; } r;
  asm("v_cvt_pk_bf16_f32 %0, %1, %2" : "=v"(r.u[0]) : "v"(a.x), "v"(a.y));
  asm("v_cvt_pk_bf16_f32 %0, %1, %2" : "=v"(r.u[1]) : "v"(a.z), "v"(a.w));
  asm("v_cvt_pk_bf16_f32 %0, %1, %2" : "=v"(r.u[2]) : "v"(b.x), "v"(b.y));
  asm("v_cvt_pk_bf16_f32 %0, %1, %2" : "=v"(r.u[3]) : "v"(b.z), "v"(b.w));
  return r.v;
}

// ---------------- one-time prep: W1^T bf16, W2^T bf16 (padded 48), zero bcnt ----------------
__global__ void k_prep(const float* __restrict__ W1, const float* __restrict__ W2,
                       unsigned short* __restrict__ w1t, unsigned short* __restrict__ w2t,
                       int* __restrict__ bcnt, int NB){
  int t = threadIdx.x;
  if(blockIdx.x == 0){
    for(int i = t; i < 8192; i += 256){
      int k = i >> 6, f = i & 63;
      w1t[f*128 + k] = f2bf(W1[i]);
    }
  } else {
    for(int i = t; i < 3072; i += 256){
      int c = i >> 6, k = i & 63;
      w2t[c*64 + k] = (c < 40) ? f2bf(W2[k*40 + c]) : (unsigned short)0;
    }
    for(int i = t; i < NB; i += 256) bcnt[i] = 0;
  }
}

// ---------------- CSR build (bucketed two-pass: locality transform for scatter) ----------------

__global__ __launch_bounds__(256) void k_bhist(const int* __restrict__ dst, int E,
                                               int* __restrict__ bcnt, int NB){
  __shared__ int l[MAXNB];
  int t = threadIdx.x;
  int base = blockIdx.x*HIST_CHUNK;
  int end = base + HIST_CHUNK; if(end > E) end = E;
  for(int b = t; b < NB; b += 256) l[b] = 0;
  __syncthreads();
  for(int i = base + t; i < end; i += 256) atomicAdd(&l[dst[i] >> BSH], 1);
  __syncthreads();
  for(int b = t; b < NB; b += 256){ int c = l[b]; if(c) atomicAdd(&bcnt[b], c); }
}

__global__ void k_bscan(const int* __restrict__ bcnt, int* __restrict__ bofs,
                        int* __restrict__ bcur, int NB, int E){
  __shared__ int sh[1024];
  int t = threadIdx.x;
  int c0 = (2*t   < NB) ? bcnt[2*t]   : 0;
  int c1 = (2*t+1 < NB) ? bcnt[2*t+1] : 0;
  sh[t] = c0 + c1; __syncthreads();
  for(int off = 1; off < 1024; off <<= 1){
    int v = (t >= off) ? sh[t - off] : 0;
    __syncthreads();
    sh[t] += v;
    __syncthreads();
  }
  int pairEx = sh[t] - (c0 + c1);
  if(2*t   < NB){ bofs[2*t]   = pairEx;      bcur[2*t]   = pairEx; }
  if(2*t+1 < NB){ bofs[2*t+1] = pairEx + c0; bcur[2*t+1] = pairEx + c0; }
  if(t == 0) bofs[NB] = E;
}

__global__ __launch_bounds__(256) void k_binpass(const int* __restrict__ src,
                          const int* __restrict__ dst, int E,
                          int* __restrict__ bcur, unsigned int* __restrict__ binned, int NB){
  __shared__ int lcnt[MAXNB];
  __shared__ int lpos[MAXNB];
  int t = threadIdx.x;
  int base = blockIdx.x * BIN_CHUNK;
  int end = base + BIN_CHUNK; if(end > E) end = E;
  for(int b = t; b < NB; b += 256) lcnt[b] = 0;
  __syncthreads();
  for(int i = base + t; i < end; i += 256)
    atomicAdd(&lcnt[dst[i] >> BSH], 1);
  __syncthreads();
  for(int b = t; b < NB; b += 256){
    int c = lcnt[b];
    lpos[b] = c ? atomicAdd(&bcur[b], c) : 0;
  }
  __syncthreads();
  for(int i = base + t; i < end; i += 256){
    int d = dst[i];
    int b = d >> BSH;
    unsigned int rec = (unsigned int)src[i] | ((unsigned int)(d & (NPB-1)) << 17);
    int p = atomicAdd(&lpos[b], 1);
    binned[p] = rec;
  }
}

// one block per 256-node bucket: LDS hist + 4-wave scan -> row_ofs, dinv, csr
__global__ __launch_bounds__(256) void k_bscatter(const unsigned int* __restrict__ binned,
     const int* __restrict__ bofs, int* __restrict__ csr, int* __restrict__ row_ofs,
     float* __restrict__ dinv, int N, int E, int NB){
  __shared__ int lcnt[NPB];
  __shared__ int lofs[NPB];
  __shared__ int lcur[NPB];
  __shared__ int wsum[4];
  int b = blockIdx.x, t = threadIdx.x;
  int beg = bofs[b], end = bofs[b+1];
  lcnt[t] = 0;
  __syncthreads();
  for(int i = beg + t; i < end; i += 256) atomicAdd(&lcnt[binned[i] >> 17], 1);
  __syncthreads();
  int c = lcnt[t];
  int lane = t & 63, wid = t >> 6;
  int v = c;
  #pragma unroll
  for(int off = 1; off < 64; off <<= 1){
    int nv = __shfl_up(v, off, 64);
    if(lane >= off) v += nv;
  }
  if(lane == 63) wsum[wid] = v;
  __syncthreads();
  int wpre = 0;
  #pragma unroll
  for(int k2 = 0; k2 < 4; k2++) if(k2 < wid) wpre += wsum[k2];
  int ex = wpre + v - c;
  lofs[t] = beg + ex; lcur[t] = 0;
  int node = (b << BSH) + t;
  if(node < N){
    row_ofs[node] = beg + ex;
    dinv[node] = rsqrtf((float)(c + 1));   // +1 self loop
  }
  __syncthreads();
  for(int i = beg + t; i < end; i += 256){
    unsigned int rec = binned[i];
    int dl = rec >> 17;
    int pos = lofs[dl] + atomicAdd(&lcur[dl], 1);
    csr[pos] = (int)(rec & 0x1FFFFu);
  }
  if(b == NB-1 && t == 0) row_ofs[N] = E;
}

// ---------------- GEMM1 (MFMA bf16): g1 = fp8( dinv * (x @ W1) ) ----------------
// 128 nodes/block. Both operands staged coalesced into LDS:
//   W1^T bf16 from prepped w1t (uint4), x via float4 + v_cvt_pk_bf16_f32.
__global__ __launch_bounds__(256) void k_gemm1(const float* __restrict__ x,
                        const unsigned short* __restrict__ w1t,
                        const float* __restrict__ dinv, unsigned int* __restrict__ g1, int n){
  __shared__ unsigned short xs[128*136];  // x tile bf16 [node][k]
  __shared__ unsigned short wt[64*136];   // W1^T bf16 [feat][k]
  int tid = threadIdx.x;
  int nodeBase = blockIdx.x*128;
  for(int i = tid; i < 1024; i += 256){
    int f = i >> 4, seg = i & 15;
    *(uint4*)&wt[f*136 + seg*8] = *(const uint4*)&w1t[f*128 + seg*8];
  }
  {
    const float4* x4 = (const float4*)x;
    for(int i = tid; i < 2048; i += 256){
      int node = i >> 4, seg = i & 15;     // 8 floats per chunk
      float4 va = make_float4(0.f,0.f,0.f,0.f), vb = va;
      if(nodeBase + node < n){
        va = x4[(size_t)(nodeBase + node)*32 + seg*2];
        vb = x4[(size_t)(nodeBase + node)*32 + seg*2 + 1];
      }
      *(bf16x8*)&xs[node*136 + seg*8] = cvt8(va, vb);
    }
  }
  __syncthreads();

  int w = tid >> 6, lane = tid & 63;
  int ml = lane & 15, q = lane >> 4;
  int n0 = nodeBase + w*32 + ml;
  int n1 = n0 + 16;
  bool vn0 = n0 < n, vn1 = n1 < n;

  f32x4 a00 = {0.f,0.f,0.f,0.f}, a01 = {0.f,0.f,0.f,0.f},
        a02 = {0.f,0.f,0.f,0.f}, a03 = {0.f,0.f,0.f,0.f};
  f32x4 a10 = {0.f,0.f,0.f,0.f}, a11 = {0.f,0.f,0.f,0.f},
        a12 = {0.f,0.f,0.f,0.f}, a13 = {0.f,0.f,0.f,0.f};
  const unsigned short* brow = &xs[(w*32 + ml)*136 + q*8];
  const unsigned short* arow = &wt[ml*136 + q*8];
  #pragma unroll
  for(int s = 0; s < 4; s++){
    bf16x8 bb0 = *(const bf16x8*)(brow +        s*32);
    bf16x8 bb1 = *(const bf16x8*)(brow + 2176 + s*32);   // +16*136
    bf16x8 a0 = *(const bf16x8*)(arow +    0 + s*32);
    bf16x8 a1 = *(const bf16x8*)(arow + 2176 + s*32);
    bf16x8 a2 = *(const bf16x8*)(arow + 4352 + s*32);
    bf16x8 a3 = *(const bf16x8*)(arow + 6528 + s*32);
    a00 = __builtin_amdgcn_mfma_f32_16x16x32_bf16(a0, bb0, a00, 0, 0, 0);
    a01 = __builtin_amdgcn_mfma_f32_16x16x32_bf16(a1, bb0, a01, 0, 0, 0);
    a02 = __builtin_amdgcn_mfma_f32_16x16x32_bf16(a2, bb0, a02, 0, 0, 0);
    a03 = __builtin_amdgcn_mfma_f32_16x16x32_bf16(a3, bb0, a03, 0, 0, 0);
    a10 = __builtin_amdgcn_mfma_f32_16x16x32_bf16(a0, bb1, a10, 0, 0, 0);
    a11 = __builtin_amdgcn_mfma_f32_16x16x32_bf16(a1, bb1, a11, 0, 0, 0);
    a12 = __builtin_amdgcn_mfma_f32_16x16x32_bf16(a2, bb1, a12, 0, 0, 0);
    a13 = __builtin_amdgcn_mfma_f32_16x16x32_bf16(a3, bb1, a13, 0, 0, 0);
  }
  if(vn0){
    float dv = dinv[n0];
    unsigned base16 = ((unsigned)n0 << 4) + q;
    int p;
    p = __builtin_amdgcn_cvt_pk_fp8_f32(a00[0]*dv, a00[1]*dv, 0, false);
    p = __builtin_amdgcn_cvt_pk_fp8_f32(a00[2]*dv, a00[3]*dv, p, true);
    g1[base16 +  0] = (unsigned)p;
    p = __builtin_amdgcn_cvt_pk_fp8_f32(a01[0]*dv, a01[1]*dv, 0, false);
    p = __builtin_amdgcn_cvt_pk_fp8_f32(a01[2]*dv, a01[3]*dv, p, true);
    g1[base16 +  4] = (unsigned)p;
    p = __builtin_amdgcn_cvt_pk_fp8_f32(a02[0]*dv, a02[1]*dv, 0, false);
    p = __builtin_amdgcn_cvt_pk_fp8_f32(a02[2]*dv, a02[3]*dv, p, true);
    g1[base16 +  8] = (unsigned)p;
    p = __builtin_amdgcn_cvt_pk_fp8_f32(a03[0]*dv, a03[1]*dv, 0, false);
    p = __builtin_amdgcn_cvt_pk_fp8_f32(a03[2]*dv, a03[3]*dv, p, true);
    g1[base16 + 12] = (unsigned)p;
  }
  if(vn1){
    float dv = dinv[n1];
    unsigned base16 = ((unsigned)n1 << 4) + q;
    int p;
    p = __builtin_amdgcn_cvt_pk_fp8_f32(a10[0]*dv, a10[1]*dv, 0, false);
    p = __builtin_amdgcn_cvt_pk_fp8_f32(a10[2]*dv, a10[3]*dv, p, true);
    g1[base16 +  0] = (unsigned)p;
    p = __builtin_amdgcn_cvt_pk_fp8_f32(a11[0]*dv, a11[1]*dv, 0, false);
    p = __builtin_amdgcn_cvt_pk_fp8_f32(a11[2]*dv, a11[3]*dv, p, true);
    g1[base16 +  4] = (unsigned)p;
    p = __builtin_amdgcn_cvt_pk_fp8_f32(a12[0]*dv, a12[1]*dv, 0, false);
    p = __builtin_amdgcn_cvt_pk_fp8_f32(a12[2]*dv, a12[3]*dv, p, true);
    g1[base16 +  8] = (unsigned)p;
    p = __builtin_amdgcn_cvt_pk_fp8_f32(a13[0]*dv, a13[1]*dv, 0, false);
    p = __builtin_amdgcn_cvt_pk_fp8_f32(a13[2]*dv, a13[3]*dv, p, true);
    g1[base16 + 12] = (unsigned)p;
  }
}

// ---------------- fused agg1 + gemm2: gather into LDS, then MFMA -> g2 ----------------
// 64 nodes/block. Phase 1: each 16-lane quarter gathers 4 nodes serially
// (lane f owns feats 4f..4f+3), u-row = bf16(dinv*relu(dinv*sum+b1)) -> LDS.
// Phase 2: 6 MFMAs/wave (classes padded to 48) -> fp8 g2 (40-B rows).
__global__ __launch_bounds__(256) void k_agg1g2(const unsigned* __restrict__ g1,
    const int* __restrict__ row_ofs, const int* __restrict__ csr,
    const float* __restrict__ dinv, const float* __restrict__ b1,
    const unsigned short* __restrict__ w2t, unsigned char* __restrict__ g2, int n){
  __shared__ unsigned short us[64*72];    // u tile bf16 [node][k]
  __shared__ unsigned short ws2[48*72];   // W2^T bf16 [class][k]
  int t = threadIdx.x;
  int nodeBase = blockIdx.x*64;
  for(int i = t; i < 384; i += 256){
    int row = i >> 3, seg = i & 7;
    *(uint4*)&ws2[row*72 + seg*8] = *(const uint4*)&w2t[row*64 + seg*8];
  }
  int lane = t & 63;
  int f = lane & 15;
  int bq = (lane & 48) << 2;              // bpermute byte-addr base of own quarter
  int qg = t >> 4;                        // quarter index in block, 0..15
  float4 bb1 = ((const float4*)b1)[f];
  #pragma unroll 1
  for(int i = 0; i < 4; i++){
    int node = nodeBase + qg*4 + i;
    int lrow = qg*4 + i;
    if(node < n){
      int beg = row_ofs[node], end = row_ofs[node+1];
      unsigned v = g1[((unsigned)node << 4) + f];        // self row (once)
      f32x2 s01 = __builtin_amdgcn_cvt_pk_f32_fp8(v, false);
      f32x2 s23 = __builtin_amdgcn_cvt_pk_f32_fp8(v, true);
      for(int e = beg; e < end; e += 16){
        int rem = end - e; if(rem > 16) rem = 16;
        int idxv = (f < rem) ? csr[e + f] : 0;
        int j = 0;
        for(; j + 4 <= rem; j += 4){
          int r0 = __builtin_amdgcn_ds_bpermute(bq + ((j+0) << 2), idxv);
          int r1 = __builtin_amdgcn_ds_bpermute(bq + ((j+1) << 2), idxv);
          int r2 = __builtin_amdgcn_ds_bpermute(bq + ((j+2) << 2), idxv);
          int r3 = __builtin_amdgcn_ds_bpermute(bq + ((j+3) << 2), idxv);
          unsigned v0 = g1[((unsigned)r0 << 4) + f];
          unsigned v1 = g1[((unsigned)r1 << 4) + f];
          unsigned v2 = g1[((unsigned)r2 << 4) + f];
          unsigned v3 = g1[((unsigned)r3 << 4) + f];
          s01 += __builtin_amdgcn_cvt_pk_f32_fp8(v0, false);
          s23 += __builtin_amdgcn_cvt_pk_f32_fp8(v0, true);
          s01 += __builtin_amdgcn_cvt_pk_f32_fp8(v1, false);
          s23 += __builtin_amdgcn_cvt_pk_f32_fp8(v1, true);
          s01 += __builtin_amdgcn_cvt_pk_f32_fp8(v2, false);
          s23 += __builtin_amdgcn_cvt_pk_f32_fp8(v2, true);
          s01 += __builtin_amdgcn_cvt_pk_f32_fp8(v3, false);
          s23 += __builtin_amdgcn_cvt_pk_f32_fp8(v3, true);
        }
        for(; j < rem; j++){
          int r0 = __builtin_amdgcn_ds_bpermute(bq + (j << 2), idxv);
          unsigned v0 = g1[((unsigned)r0 << 4) + f];
          s01 += __builtin_amdgcn_cvt_pk_f32_fp8(v0, false);
          s23 += __builtin_amdgcn_cvt_pk_f32_fp8(v0, true);
        }
      }
      float dv = dinv[node];
      float h0 = fmaxf(fmaf(dv, s01.x, bb1.x), 0.f);
      float h1 = fmaxf(fmaf(dv, s01.y, bb1.y), 0.f);
      float h2 = fmaxf(fmaf(dv, s23.x, bb1.z), 0.f);
      float h3 = fmaxf(fmaf(dv, s23.y, bb1.w), 0.f);
      unsigned p0, p1;
      asm("v_cvt_pk_bf16_f32 %0, %1, %2" : "=v"(p0) : "v"(dv*h0), "v"(dv*h1));
      asm("v_cvt_pk_bf16_f32 %0, %1, %2" : "=v"(p1) : "v"(dv*h2), "v"(dv*h3));
      *(uint2*)&us[lrow*72 + f*4] = make_uint2(p0, p1);
    } else {
      *(uint2*)&us[lrow*72 + f*4] = make_uint2(0u, 0u);
    }
  }
  __syncthreads();
  // ---- MFMA phase (classes padded to 48) ----
  int w = t >> 6;
  int ml = lane & 15, q = lane >> 4;
  f32x4 acc0 = {0.f,0.f,0.f,0.f}, acc1 = {0.f,0.f,0.f,0.f}, acc2 = {0.f,0.f,0.f,0.f};
  const unsigned short* brow = &us[(w*16 + ml)*72 + q*8];
  const unsigned short* a0r = &ws2[ml*72 + q*8];
  #pragma unroll
  for(int s = 0; s < 2; s++){
    bf16x8 bb = *(const bf16x8*)(brow + s*32);
    bf16x8 a0 = *(const bf16x8*)(a0r +    0 + s*32);
    bf16x8 a1 = *(const bf16x8*)(a0r + 1152 + s*32);   // +16*72
    bf16x8 a2 = *(const bf16x8*)(a0r + 2304 + s*32);   // +32*72
    acc0 = __builtin_amdgcn_mfma_f32_16x16x32_bf16(a0, bb, acc0, 0, 0, 0);
    acc1 = __builtin_amdgcn_mfma_f32_16x16x32_bf16(a1, bb, acc1, 0, 0, 0);
    acc2 = __builtin_amdgcn_mfma_f32_16x16x32_bf16(a2, bb, acc2, 0, 0, 0);
  }
  // D: col = node (ml), row = class = ctile*16 + q*4 + r -> row dword = ctile*4 + q
  int node = nodeBase + w*16 + ml;
  if(node < n){
    unsigned* gd = (unsigned*)g2;
    unsigned rb = (unsigned)node*10u + q;
    int p;
    p = __builtin_amdgcn_cvt_pk_fp8_f32(acc0[0], acc0[1], 0, false);
    p = __builtin_amdgcn_cvt_pk_fp8_f32(acc0[2], acc0[3], p, true);
    gd[rb + 0] = (unsigned)p;
    p = __builtin_amdgcn_cvt_pk_fp8_f32(acc1[0], acc1[1], 0, false);
    p = __builtin_amdgcn_cvt_pk_fp8_f32(acc1[2], acc1[3], p, true);
    gd[rb + 4] = (unsigned)p;
    if(q < 2){
      p = __builtin_amdgcn_cvt_pk_fp8_f32(acc2[0], acc2[1], 0, false);
      p = __builtin_amdgcn_cvt_pk_fp8_f32(acc2[2], acc2[3], p, true);
      gd[rb + 8] = (unsigned)p;
    }
  }
}

// ---------------- agg2: node-per-quarter gather + bias + log_softmax ----------------
__global__ __launch_bounds__(256) void k_agg2(const unsigned char* __restrict__ g2,
     const int* __restrict__ row_ofs, const int* __restrict__ csr,
     const float* __restrict__ dinv, const float* __restrict__ b2,
     float* __restrict__ out, int N){
  int t = threadIdx.x;
  int lane = t & 63;
  int f = lane & 15;
  int fc = (f < 10) ? f : 0;              // f>=10 lanes duplicate dword0, discarded
  int bq = (lane & 48) << 2;
  int node = blockIdx.x*16 + (t >> 4);
  if(node >= N) return;
  int beg = row_ofs[node], end = row_ofs[node+1];
  const unsigned* gd = (const unsigned*)g2;   // row = 10 dwords (40 fp8)
  unsigned v = gd[(unsigned)node*10u + fc];   // self row
  f32x2 s01 = __builtin_amdgcn_cvt_pk_f32_fp8(v, false);
  f32x2 s23 = __builtin_amdgcn_cvt_pk_f32_fp8(v, true);
  for(int e = beg; e < end; e += 16){
    int rem = end - e; if(rem > 16) rem = 16;
    int idxv = (f < rem) ? csr[e + f] : 0;
    int j = 0;
    for(; j + 4 <= rem; j += 4){
      int r0 = __builtin_amdgcn_ds_bpermute(bq + ((j+0) << 2), idxv);
      int r1 = __builtin_amdgcn_ds_bpermute(bq + ((j+1) << 2), idxv);
      int r2 = __builtin_amdgcn_ds_bpermute(bq + ((j+2) << 2), idxv);
      int r3 = __builtin_amdgcn_ds_bpermute(bq + ((j+3) << 2), idxv);
      unsigned v0 = gd[(unsigned)r0*10u + fc];
      unsigned v1 = gd[(unsigned)r1*10u + fc];
      unsigned v2 = gd[(unsigned)r2*10u + fc];
      unsigned v3 = gd[(unsigned)r3*10u + fc];
      s01 += __builtin_amdgcn_cvt_pk_f32_fp8(v0, false);
      s23 += __builtin_amdgcn_cvt_pk_f32_fp8(v0, true);
      s01 += __builtin_amdgcn_cvt_pk_f32_fp8(v1, false);
      s23 += __builtin_amdgcn_cvt_pk_f32_fp8(v1, true);
      s01 += __builtin_amdgcn_cvt_pk_f32_fp8(v2, false);
      s23 += __builtin_amdgcn_cvt_pk_f32_fp8(v2, true);
      s01 += __builtin_amdgcn_cvt_pk_f32_fp8(v3, false);
      s23 += __builtin_amdgcn_cvt_pk_f32_fp8(v3, true);
    }
    for(; j < rem; j++){
      int r0 = __builtin_amdgcn_ds_bpermute(bq + (j << 2), idxv);
      unsigned v0 = gd[(unsigned)r0*10u + fc];
      s01 += __builtin_amdgcn_cvt_pk_f32_fp8(v0, false);
      s23 += __builtin_amdgcn_cvt_pk_f32_fp8(v0, true);
    }
  }
  float dv = dinv[node];
  float4 bb = ((const float4*)b2)[fc];
  float l0 = fmaf(dv, s01.x, bb.x);
  float l1 = fmaf(dv, s01.y, bb.y);
  float l2 = fmaf(dv, s23.x, bb.z);
  float l3 = fmaf(dv, s23.y, bb.w);
  bool valid = (f < 10);
  float m = valid ? fmaxf(fmaxf(l0,l1), fmaxf(l2,l3)) : -INFINITY;
  m = fmaxf(m, __shfl_xor(m,1,64)); m = fmaxf(m, __shfl_xor(m,2,64));
  m = fmaxf(m, __shfl_xor(m,4,64)); m = fmaxf(m, __shfl_xor(m,8,64));
  float ex = valid ? (expf(l0-m)+expf(l1-m)) + (expf(l2-m)+expf(l3-m)) : 0.f;
  ex += __shfl_xor(ex,1,64); ex += __shfl_xor(ex,2,64);
  ex += __shfl_xor(ex,4,64); ex += __shfl_xor(ex,8,64);
  float ll = logf(ex);
  if(valid){
    ((float4*)out)[(unsigned)node*10u + f] = make_float4(l0-m-ll, l1-m-ll, l2-m-ll, l3-m-ll);
  }
}

// ---------------- launch ----------------

extern "C" void kernel_launch(void* const* d_in, const int* in_sizes, int n_in,
                              void* d_out, int out_size, void* d_ws, size_t ws_size,
                              hipStream_t stream){
  const float* x  = (const float*)d_in[0];
  const int*   ei = (const int*)  d_in[1];
  const float* W1 = (const float*)d_in[2];
  const float* b1 = (const float*)d_in[3];
  const float* W2 = (const float*)d_in[4];
  const float* b2 = (const float*)d_in[5];
  float* out = (float*)d_out;

  int N = in_sizes[0] / 128;        // 100000
  int E = in_sizes[1] / 2;          // 1600000
  const int* src = ei;
  const int* dst = ei + E;
  int NB = (N + NPB - 1) >> BSH;    // 391

  char* w = (char*)d_ws;
  auto alloc = [&](size_t bytes) -> char* {
    char* p = w;
    w += (bytes + 511) & ~(size_t)511;
    return p;
  };
  int*   bcnt    = (int*)  alloc((size_t)NB*4);
  int*   bofs    = (int*)  alloc((size_t)(NB+1)*4);
  int*   bcur    = (int*)  alloc((size_t)NB*4);
  int*   row_ofs = (int*)  alloc((size_t)(N+1)*4);
  float* dinv    = (float*)alloc((size_t)N*4);
  unsigned int* binned = (unsigned int*)alloc((size_t)E*4);
  int*   csr     = (int*)  alloc((size_t)E*4);
  unsigned int*   g1 = (unsigned int*)  alloc((size_t)N*64);   // fp8, 64 B rows
  unsigned char*  g2 = (unsigned char*) alloc((size_t)N*40);   // fp8, 40 B rows
  unsigned short* w1t = (unsigned short*)alloc((size_t)64*128*2); // W1^T bf16
  unsigned short* w2t = (unsigned short*)alloc((size_t)48*64*2);  // W2^T bf16 (padded)

  k_prep    <<<2, 256, 0, stream>>>(W1, W2, w1t, w2t, bcnt, NB);
  k_bhist   <<<(E+HIST_CHUNK-1)/HIST_CHUNK, 256, 0, stream>>>(dst, E, bcnt, NB);
  k_bscan   <<<1, 1024, 0, stream>>>(bcnt, bofs, bcur, NB, E);
  k_binpass <<<(E+BIN_CHUNK-1)/BIN_CHUNK, 256, 0, stream>>>(src, dst, E, bcur, binned, NB);
  k_bscatter<<<NB, 256, 0, stream>>>(binned, bofs, csr, row_ofs, dinv, N, E, NB);

  k_gemm1   <<<(N+127)/128, 256, 0, stream>>>(x, w1t, dinv, g1, N);
  k_agg1g2  <<<(N+63)/64, 256, 0, stream>>>(g1, row_ofs, csr, dinv, b1, w2t, g2, N);
  k_agg2    <<<(N+15)/16, 256, 0, stream>>>(g2, row_ofs, csr, dinv, b2, out, N);
}